// Round 7
// baseline (292.194 us; speedup 1.0000x reference)
//
#include <hip/hip_runtime.h>
#include <hip/hip_fp16.h>

#define N_NODES 50000
#define N_EDGES 800000
#define IN_FEATS 128
#define HD 128            // HEADS*OUT_FEATS
#define LOG2E 1.4426950408889634f

#define NB1 200           // pass-1 radix blocks
#define EPB1 4000         // edges per pass-1 block (200*4000 == E exactly)
#define NBUK 196          // buckets = ceil(N_NODES/256)
#define MTAB (NBUK * NB1) // 39200 histogram table entries (u16)
#define EBUF 6144         // LDS edge staging per bucket (mean 4081, max ~4400)
#define PREPN 192         // prep blocks (192*256 == 24*4*64*8)
#define PGRID 782         // proj blocks = ceil((N_NODES/16)/4)

typedef __attribute__((ext_vector_type(8))) short bf16x8;
typedef __attribute__((ext_vector_type(4))) float floatx4;

#if __has_builtin(__builtin_amdgcn_exp2f)
#define EXP2F(x) __builtin_amdgcn_exp2f(x)
#else
#define EXP2F(x) __expf((x) * 0.6931471805599453f)
#endif

static __device__ __forceinline__ unsigned short f2bf(float x) {
    unsigned int u = __float_as_uint(x);
    return (unsigned short)((u + 0x7FFFu + ((u >> 16) & 1u)) >> 16);   // RN-even
}
static __device__ __forceinline__ float bf2f(unsigned short h) {
    return __uint_as_float((unsigned int)h << 16);
}
static __device__ __forceinline__ unsigned int pk(float a, float b) {
    return (unsigned int)__half_as_ushort(__float2half(a)) |
           ((unsigned int)__half_as_ushort(__float2half(b)) << 16);
}

// ---------------------------------------------------------------------------
// K1: prep (weight swizzle into MFMA A-fragment order, log2e pre-scale) +
//     pass-1 radix histogram of dst>>8 (LDS atomics, u16 table).
// ---------------------------------------------------------------------------
__global__ __launch_bounds__(256) void prep_hist_kernel(
    const float* __restrict__ W0, const float* __restrict__ W1,
    const float* __restrict__ W2, unsigned short* __restrict__ Bsw,
    const int* __restrict__ dst, unsigned short* __restrict__ Htab) {
    __shared__ int h[NBUK];
    if (blockIdx.x < PREPN) {
        int idx = blockIdx.x * 256 + threadIdx.x;    // < 49152 exactly
        int j = idx & 7;
        int l = (idx >> 3) & 63;
        int q = (idx >> 9) & 3;
        int t = idx >> 11;                           // 0..23
        int k = q * 32 + ((l >> 4) << 3) + j;
        int c = ((t & 7) << 4) + (l & 15);
        int m = t >> 3;
        const float* W = (m == 0) ? W0 : ((m == 1) ? W1 : W2);
        float w = W[(size_t)c * IN_FEATS + k];
        if (m < 2) w *= LOG2E;
        Bsw[idx] = f2bf(w);
        return;
    }
    int blk = blockIdx.x - PREPN;                    // 0..NB1-1
    for (int i = threadIdx.x; i < NBUK; i += 256) h[i] = 0;
    __syncthreads();
    int base = blk * EPB1;
    for (int i = threadIdx.x; i < EPB1; i += 256)
        atomicAdd(&h[dst[base + i] >> 8], 1);
    __syncthreads();
    for (int b = threadIdx.x; b < NBUK; b += 256)
        Htab[b * NB1 + blk] = (unsigned short)h[b];  // counts <= 4000 < 65536
}

// ---------------------------------------------------------------------------
// K2: fused MFMA projection + pass-1 scatter.
// Proj blocks (< PGRID): D = W . feat^T via mfma_16x16x32_bf16 (hi/lo split);
//   each lane ends with 4 consecutive channels of one node -> dwordx4 to gsv
//   (fs/fv fp16 interleaved), dwordx2 to fdh.
// Scatter blocks: self-compute their prefix bases by a tiled block-scan over
//   the full u16 Htab (capturing positions f % NB1 == blk), then counting-sort
//   edges into tmp = (dst&255)<<16 | src via LDS cursors. Zero global atomics.
// ---------------------------------------------------------------------------
__global__ __launch_bounds__(256) void proj_scatter_kernel(
    const float* __restrict__ feat, const unsigned short* __restrict__ Bsw,
    const float* __restrict__ b_src, const float* __restrict__ b_dst,
    const float* __restrict__ b_v,
    unsigned short* __restrict__ gsv, unsigned short* __restrict__ fdh,
    const int* __restrict__ src, const int* __restrict__ dst,
    const unsigned short* __restrict__ Htab, unsigned int* __restrict__ tmp) {
    __shared__ int Sl[NBUK];
    __shared__ int curl[NBUK];
    __shared__ int wsums[4];
    __shared__ int sbase;
    if (blockIdx.x >= PGRID) {
        int blk = blockIdx.x - PGRID;
        int t = threadIdx.x, lane = t & 63, w = t >> 6;
        if (t == 0) sbase = 0;
        __syncthreads();
        for (int T = 0; T < MTAB; T += 256) {
            int f = T + t;
            int v = (f < MTAB) ? (int)Htab[f] : 0;
            int x = v;
#pragma unroll
            for (int d = 1; d < 64; d <<= 1) {
                int up = __shfl_up(x, d);
                if (lane >= d) x += up;
            }
            if (lane == 63) wsums[w] = x;
            __syncthreads();                         // wsums ready
            int base = sbase;
            for (int ww = 0; ww < w; ++ww) base += wsums[ww];
            int tile_total = wsums[0] + wsums[1] + wsums[2] + wsums[3];
            if (f < MTAB) {
                int bq = f / NB1;
                if (f - bq * NB1 == blk) Sl[bq] = base + x - v;   // excl prefix
            }
            __syncthreads();                         // all read sbase/wsums
            if (t == 0) sbase += tile_total;
        }
        __syncthreads();
        for (int bb = t; bb < NBUK; bb += 256) curl[bb] = Sl[bb];
        __syncthreads();
        int ebase = blk * EPB1;
        for (int i = t; i < EPB1; i += 256) {
            int d = dst[ebase + i];
            int s = src[ebase + i];
            int p = atomicAdd(&curl[d >> 8], 1);     // LDS atomic
            tmp[p] = (unsigned int)s | ((unsigned int)(d & 255) << 16);
        }
        return;
    }
    int wave = threadIdx.x >> 6, lane = threadIdx.x & 63;
    int tile = blockIdx.x * 4 + wave;
    if (tile >= N_NODES / 16) return;
    int row0 = tile * 16;
    int r16 = lane & 15, quad = lane >> 4;
    size_t node = (size_t)(row0 + r16);

    bf16x8 Fh[4], Fl[4];
    const float* frow = feat + node * IN_FEATS + quad * 8;
#pragma unroll
    for (int q = 0; q < 4; ++q) {
        float4 x0 = *(const float4*)(frow + q * 32);
        float4 x1 = *(const float4*)(frow + q * 32 + 4);
        float xs[8] = {x0.x, x0.y, x0.z, x0.w, x1.x, x1.y, x1.z, x1.w};
#pragma unroll
        for (int j = 0; j < 8; ++j) {
            unsigned short hh = f2bf(xs[j]);
            Fh[q][j] = (short)hh;
            Fl[q][j] = (short)f2bf(xs[j] - bf2f(hh));
        }
    }

#pragma unroll 1
    for (int tt = 0; tt < 8; ++tt) {
        floatx4 as = {0.f,0.f,0.f,0.f}, ad = {0.f,0.f,0.f,0.f}, av = {0.f,0.f,0.f,0.f};
#pragma unroll
        for (int q = 0; q < 4; ++q) {
            bf16x8 ws = *(const bf16x8*)(Bsw + ((((tt)      * 4 + q) * 64 + lane) << 3));
            bf16x8 wd = *(const bf16x8*)(Bsw + ((((8 + tt)  * 4 + q) * 64 + lane) << 3));
            bf16x8 wv = *(const bf16x8*)(Bsw + ((((16 + tt) * 4 + q) * 64 + lane) << 3));
            as = __builtin_amdgcn_mfma_f32_16x16x32_bf16(ws, Fh[q], as, 0, 0, 0);
            as = __builtin_amdgcn_mfma_f32_16x16x32_bf16(ws, Fl[q], as, 0, 0, 0);
            ad = __builtin_amdgcn_mfma_f32_16x16x32_bf16(wd, Fh[q], ad, 0, 0, 0);
            ad = __builtin_amdgcn_mfma_f32_16x16x32_bf16(wd, Fl[q], ad, 0, 0, 0);
            av = __builtin_amdgcn_mfma_f32_16x16x32_bf16(wv, Fh[q], av, 0, 0, 0);
            av = __builtin_amdgcn_mfma_f32_16x16x32_bf16(wv, Fl[q], av, 0, 0, 0);
        }
        int cbase = (tt << 4) + (quad << 2);
        float4 bs = *(const float4*)(b_src + cbase);
        float4 bd = *(const float4*)(b_dst + cbase);
        float4 bv = *(const float4*)(b_v   + cbase);
        uint4 o;
        o.x = pk(as[0] + bs.x * LOG2E, as[1] + bs.y * LOG2E);
        o.y = pk(av[0] + bv.x,         av[1] + bv.y);
        o.z = pk(as[2] + bs.z * LOG2E, as[3] + bs.w * LOG2E);
        o.w = pk(av[2] + bv.z,         av[3] + bv.w);
        *(uint4*)(gsv + node * 256 + (cbase << 1)) = o;
        uint2 od;
        od.x = pk(ad[0] + bd.x * LOG2E, ad[1] + bd.y * LOG2E);
        od.y = pk(ad[2] + bd.z * LOG2E, ad[3] + bd.w * LOG2E);
        *(uint2*)(fdh + node * 128 + cbase) = od;
    }
}

// ---------------------------------------------------------------------------
// K3: pass-2 bin. One block per bucket (256 dst nodes). Computes its own
// start/end by block-reduce over the u16 Htab, stages edges + sorted output
// in LDS, flushes ssort coalesced. Emits off[].
// ---------------------------------------------------------------------------
__global__ __launch_bounds__(256) void bin_kernel(
    const unsigned int* __restrict__ tmp, const unsigned short* __restrict__ Htab,
    int* __restrict__ off, int* __restrict__ ssort) {
    __shared__ unsigned int ebuf[EBUF];
    __shared__ unsigned short obuf[EBUF];
    __shared__ int cnt_l[256];
    __shared__ int wsum[4];
    __shared__ int sred[8];
    int b = blockIdx.x, t = threadIdx.x, lane = t & 63, w = t >> 6;

    // start/end via block reduce of Htab[0 .. (b+1)*NB1)
    int lo = b * NB1, hi = lo + NB1;
    int sAll = 0, sBuk = 0;
    for (int f = t; f < hi; f += 256) {
        int v = (int)Htab[f];
        sAll += v;
        sBuk += (f >= lo) ? v : 0;
    }
#pragma unroll
    for (int d = 32; d > 0; d >>= 1) {
        sAll += __shfl_down(sAll, d);
        sBuk += __shfl_down(sBuk, d);
    }
    if (lane == 0) { sred[w] = sAll; sred[4 + w] = sBuk; }
    cnt_l[t] = 0;
    __syncthreads();
    int end  = sred[0] + sred[1] + sred[2] + sred[3];
    int btot = sred[4] + sred[5] + sred[6] + sred[7];
    int start = end - btot;
    int cnt0 = btot;

    bool staged = (cnt0 <= EBUF);
    for (int i = t; i < cnt0; i += 256) {
        unsigned int e = tmp[start + i];
        if (staged) ebuf[i] = e;
        atomicAdd(&cnt_l[e >> 16], 1);
    }
    __syncthreads();
    int v = cnt_l[t];
    int x = v;
#pragma unroll
    for (int d = 1; d < 64; d <<= 1) { int up = __shfl_up(x, d); if (lane >= d) x += up; }
    if (lane == 63) wsum[w] = x;
    __syncthreads();
    int basex = 0;
    for (int ww = 0; ww < w; ++ww) basex += wsum[ww];
    int excl = basex + x - v;                  // exclusive within bucket
    int node = b * 256 + t;
    if (node < N_NODES) off[node] = start + excl;
    if (b == NBUK - 1 && t == 0) { off[N_NODES] = N_EDGES; ssort[N_EDGES] = 0; }
    __syncthreads();
    cnt_l[t] = excl;                           // becomes cursor
    __syncthreads();
    if (staged) {
        for (int i = t; i < cnt0; i += 256) {
            unsigned int e = ebuf[i];
            int p = atomicAdd(&cnt_l[e >> 16], 1);
            obuf[p] = (unsigned short)(e & 0xFFFFu);
        }
        __syncthreads();
        for (int i = t; i < cnt0; i += 256)    // coalesced flush
            ssort[start + i] = (int)obuf[i];
    } else {
        for (int i = t; i < cnt0; i += 256) {
            unsigned int e = tmp[start + i];
            int p = atomicAdd(&cnt_l[e >> 16], 1);
            ssort[start + p] = (int)(e & 0xFFFFu);
        }
    }
}

// ---------------------------------------------------------------------------
// K4: gather. One wave per dst node (2 waves/block for tail balance), channel
// pair per lane; two independent pipelined edge streams (ILP-2); fp32 logit
// math; exp2 (weights pre-scaled by log2e).
// ---------------------------------------------------------------------------
__global__ __launch_bounds__(128) void gather_kernel(
    const unsigned short* __restrict__ gsv, const unsigned short* __restrict__ fdh,
    const int* __restrict__ off, const int* __restrict__ ssort,
    float* __restrict__ out, int n) {
    int wid = __builtin_amdgcn_readfirstlane((int)((blockIdx.x * 128 + threadIdx.x) >> 6));
    int lane = threadIdx.x & 63;
    if (wid >= n) return;
    float2 fd = __half22float2(*(const __half2*)(fdh + (size_t)wid * 128 + lane * 2));

    float nxA = 0.f, nyA = 0.f, dxA = 0.f, dyA = 0.f;
    float nxB = 0.f, nyB = 0.f, dxB = 0.f, dyB = 0.f;
    int beg = off[wid], end = off[wid + 1];
    int mid = (beg + end) >> 1;
    int LA = mid - beg, LB = end - mid;        // LB == LA or LA+1

#define EDGE_UPD(g, valid, dxv, dyv, nxv, nyv) {                              \
        float2 fs = __half22float2(*(const __half2*)&(g).x);                  \
        float a0 = fs.x + fd.x, a1 = fs.y + fd.y;                             \
        a0 = fmaf(fminf(a0, 0.f), -0.8f, a0);                                 \
        a1 = fmaf(fminf(a1, 0.f), -0.8f, a1);                                 \
        float x0 = EXP2F(a0), x1 = EXP2F(a1);                                 \
        if (!(valid)) { x0 = 0.f; x1 = 0.f; }                                 \
        float2 fv = __half22float2(*(const __half2*)&(g).y);                  \
        dxv += x0; dyv += x1;                                                 \
        nxv = fmaf(x0, fv.x, nxv); nyv = fmaf(x1, fv.y, nyv); }

    if (LB > 0) {
        int sA = ssort[beg];
        int sB = ssort[mid];
        uint2 gA = *(const uint2*)(gsv + (size_t)sA * 256 + lane * 4);
        uint2 gB = *(const uint2*)(gsv + (size_t)sB * 256 + lane * 4);
        for (int k = 0; k < LB - 1; ++k) {
            int sA2 = ssort[beg + k + 1];      // <= mid <= E, always safe
            int sB2 = ssort[mid + k + 1];      // <= end <= E, always safe
            uint2 gA2 = *(const uint2*)(gsv + (size_t)sA2 * 256 + lane * 4);
            uint2 gB2 = *(const uint2*)(gsv + (size_t)sB2 * 256 + lane * 4);
            EDGE_UPD(gA, 1, dxA, dyA, nxA, nyA);
            EDGE_UPD(gB, 1, dxB, dyB, nxB, nyB);
            gA = gA2; gB = gB2;
        }
        EDGE_UPD(gA, (LB - 1) < LA, dxA, dyA, nxA, nyA);
        EDGE_UPD(gB, 1, dxB, dyB, nxB, nyB);
    }
    float dx = dxA + dxB, dy = dyA + dyB;
    float nx = nxA + nxB, ny = nyA + nyB;
    float2 o;
    o.x = (dx > 0.f) ? nx / dx : 0.f;
    o.y = (dy > 0.f) ? ny / dy : 0.f;
    *(float2*)&out[(size_t)wid * HD + lane * 2] = o;
#undef EDGE_UPD
}

// ---------------------------------------------------------------------------
extern "C" void kernel_launch(void* const* d_in, const int* in_sizes, int n_in,
                              void* d_out, int out_size, void* d_ws, size_t ws_size,
                              hipStream_t stream) {
    const float* feat  = (const float*)d_in[0];
    const float* W_src = (const float*)d_in[1];
    const float* b_src = (const float*)d_in[2];
    const float* W_dst = (const float*)d_in[3];
    const float* b_dst = (const float*)d_in[4];
    const float* W_v   = (const float*)d_in[5];
    const float* b_v   = (const float*)d_in[6];
    const int*   src   = (const int*)d_in[7];
    const int*   dst   = (const int*)d_in[8];
    float* out = (float*)d_out;

    // workspace layout
    unsigned short* gsv  = (unsigned short*)d_ws;                // N*256 u16
    unsigned short* fdh  = gsv + (size_t)N_NODES * 256;          // N*128 u16
    unsigned short* Bsw  = fdh + (size_t)N_NODES * 128;          // 49152 u16
    unsigned short* Htab = Bsw + 24 * 4 * 64 * 8;                // MTAB u16
    int* off   = (int*)(Htab + MTAB + (MTAB & 1));               // N+1
    int* ssort = off + (N_NODES + 1);                            // E+1
    unsigned int* tmp = (unsigned int*)(ssort + N_EDGES + 1);    // E

    prep_hist_kernel<<<PREPN + NB1, 256, 0, stream>>>(W_src, W_dst, W_v, Bsw, dst, Htab);

    proj_scatter_kernel<<<PGRID + NB1, 256, 0, stream>>>(
        feat, Bsw, b_src, b_dst, b_v, gsv, fdh, src, dst, Htab, tmp);

    bin_kernel<<<NBUK, 256, 0, stream>>>(tmp, Htab, off, ssort);

    gather_kernel<<<(N_NODES * 64) / 128, 128, 0, stream>>>(gsv, fdh, off, ssort, out, N_NODES);
}

// Round 8
// 190.848 us; speedup vs baseline: 1.5310x; 1.5310x over previous
//
#include <hip/hip_runtime.h>
#include <hip/hip_fp16.h>

#define N_NODES 50000
#define N_EDGES 800000
#define IN_FEATS 128
#define HD 128            // HEADS*OUT_FEATS
#define LOG2E 1.4426950408889634f

#define NB1 200           // pass-1 radix blocks
#define EPB1 4000         // edges per pass-1 block (200*4000 == E exactly)
#define NBUK 196          // buckets = ceil(N_NODES/256)
#define MTAB (NBUK * NB1) // 39200 histogram table entries (u16)
#define MB_SCAN 154       // ceil(MTAB/256)
#define EBUF 6144         // LDS edge staging per bucket (mean 4081, max ~4400)
#define PREPN 192         // prep blocks (192*256 == 24*4*64*8)
#define PGRID 782         // proj blocks = ceil((N_NODES/16)/4)

typedef __attribute__((ext_vector_type(8))) short bf16x8;
typedef __attribute__((ext_vector_type(4))) float floatx4;

#if __has_builtin(__builtin_amdgcn_exp2f)
#define EXP2F(x) __builtin_amdgcn_exp2f(x)
#else
#define EXP2F(x) __expf((x) * 0.6931471805599453f)
#endif

static __device__ __forceinline__ unsigned short f2bf(float x) {
    unsigned int u = __float_as_uint(x);
    return (unsigned short)((u + 0x7FFFu + ((u >> 16) & 1u)) >> 16);   // RN-even
}
static __device__ __forceinline__ float bf2f(unsigned short h) {
    return __uint_as_float((unsigned int)h << 16);
}
static __device__ __forceinline__ unsigned int pk(float a, float b) {
    return (unsigned int)__half_as_ushort(__float2half(a)) |
           ((unsigned int)__half_as_ushort(__float2half(b)) << 16);
}

// ---------------------------------------------------------------------------
// K1: prep (weight swizzle into MFMA A-fragment order, log2e pre-scale) +
//     pass-1 radix histogram of dst>>8 (LDS atomics, u16 table).
// ---------------------------------------------------------------------------
__global__ __launch_bounds__(256) void prep_hist_kernel(
    const float* __restrict__ W0, const float* __restrict__ W1,
    const float* __restrict__ W2, unsigned short* __restrict__ Bsw,
    const int* __restrict__ dst, unsigned short* __restrict__ Htab) {
    __shared__ int h[NBUK];
    if (blockIdx.x < PREPN) {
        int idx = blockIdx.x * 256 + threadIdx.x;    // < 49152 exactly
        int j = idx & 7;
        int l = (idx >> 3) & 63;
        int q = (idx >> 9) & 3;
        int t = idx >> 11;                           // 0..23
        int k = q * 32 + ((l >> 4) << 3) + j;
        int c = ((t & 7) << 4) + (l & 15);
        int m = t >> 3;
        const float* W = (m == 0) ? W0 : ((m == 1) ? W1 : W2);
        float w = W[(size_t)c * IN_FEATS + k];
        if (m < 2) w *= LOG2E;
        Bsw[idx] = f2bf(w);
        return;
    }
    int blk = blockIdx.x - PREPN;                    // 0..NB1-1
    for (int i = threadIdx.x; i < NBUK; i += 256) h[i] = 0;
    __syncthreads();
    int base = blk * EPB1;
    for (int i = threadIdx.x; i < EPB1; i += 256)
        atomicAdd(&h[dst[base + i] >> 8], 1);
    __syncthreads();
    for (int b = threadIdx.x; b < NBUK; b += 256)
        Htab[b * NB1 + blk] = (unsigned short)h[b];  // counts <= 4000 < 65536
}

// ---------------------------------------------------------------------------
// K2: scan phase 1 — per-block sums (256 entries each) of u16 Htab
// ---------------------------------------------------------------------------
__global__ __launch_bounds__(256) void scan_partial(const unsigned short* __restrict__ cnt,
                                                    int* __restrict__ bsum, int n) {
    int i = blockIdx.x * 256 + threadIdx.x;
    int v = (i < n) ? (int)cnt[i] : 0;
#pragma unroll
    for (int d = 32; d > 0; d >>= 1) v += __shfl_down(v, d);
    __shared__ int ws[4];
    int lane = threadIdx.x & 63, w = threadIdx.x >> 6;
    if (lane == 0) ws[w] = v;
    __syncthreads();
    if (threadIdx.x == 0) bsum[blockIdx.x] = ws[0] + ws[1] + ws[2] + ws[3];
}

// ---------------------------------------------------------------------------
// K3: scan phase 2 — every block redundantly reduces bsum for its base, then
// writes its 256 exclusive offsets; last block writes grand total at out[n].
// ---------------------------------------------------------------------------
__global__ __launch_bounds__(256) void scan_write2(const unsigned short* __restrict__ cnt,
                                                   const int* __restrict__ bsum,
                                                   int* __restrict__ outp, int n, int nb) {
    int t = threadIdx.x, b = blockIdx.x;
    int va = (t < nb) ? bsum[t] : 0;
    int vb = (t < b) ? va : 0;
    int ra = va, rb = vb;
#pragma unroll
    for (int d = 32; d > 0; d >>= 1) { ra += __shfl_down(ra, d); rb += __shfl_down(rb, d); }
    __shared__ int sa[4], sb[4], ws2[4];
    int lane = t & 63, w = t >> 6;
    if (lane == 0) { sa[w] = ra; sb[w] = rb; }
    __syncthreads();
    int total = sa[0] + sa[1] + sa[2] + sa[3];
    int base  = sb[0] + sb[1] + sb[2] + sb[3];
    int i = b * 256 + t;
    int v = (i < n) ? (int)cnt[i] : 0;
    int x = v;
#pragma unroll
    for (int d = 1; d < 64; d <<= 1) { int up = __shfl_up(x, d); if (lane >= d) x += up; }
    if (lane == 63) ws2[w] = x;
    __syncthreads();
    for (int ww = 0; ww < w; ++ww) base += ws2[ww];
    if (i < n) outp[i] = base + x - v;
    if (b == (int)gridDim.x - 1 && t == 0) outp[n] = total;
}

// ---------------------------------------------------------------------------
// K4: fused MFMA projection + pass-1 scatter (scatter uses PRECOMPUTED HtabS —
// no in-kernel scan; that serial scan was round 7's 137 us regression).
// Proj blocks (< PGRID): D = W . feat^T via mfma_16x16x32_bf16 (hi/lo split);
//   each lane ends with 4 consecutive channels of one node -> dwordx4 to gsv
//   (fs/fv fp16 interleaved), dwordx2 to fdh.
// Scatter blocks: counting-sort edges into tmp = (dst&255)<<16 | src using
//   LDS cursors seeded from HtabS. Zero global atomics.
// ---------------------------------------------------------------------------
__global__ __launch_bounds__(256) void proj_scatter_kernel(
    const float* __restrict__ feat, const unsigned short* __restrict__ Bsw,
    const float* __restrict__ b_src, const float* __restrict__ b_dst,
    const float* __restrict__ b_v,
    unsigned short* __restrict__ gsv, unsigned short* __restrict__ fdh,
    const int* __restrict__ src, const int* __restrict__ dst,
    const int* __restrict__ HtabS, unsigned int* __restrict__ tmp) {
    __shared__ int curl[NBUK];
    if (blockIdx.x >= PGRID) {
        int blk = blockIdx.x - PGRID;
        for (int b = threadIdx.x; b < NBUK; b += 256) curl[b] = HtabS[b * NB1 + blk];
        __syncthreads();
        int ebase = blk * EPB1;
        for (int i = threadIdx.x; i < EPB1; i += 256) {
            int d = dst[ebase + i];
            int s = src[ebase + i];
            int p = atomicAdd(&curl[d >> 8], 1);     // LDS atomic
            tmp[p] = (unsigned int)s | ((unsigned int)(d & 255) << 16);
        }
        return;
    }
    int wave = threadIdx.x >> 6, lane = threadIdx.x & 63;
    int tile = blockIdx.x * 4 + wave;
    if (tile >= N_NODES / 16) return;
    int row0 = tile * 16;
    int r16 = lane & 15, quad = lane >> 4;
    size_t node = (size_t)(row0 + r16);

    bf16x8 Fh[4], Fl[4];
    const float* frow = feat + node * IN_FEATS + quad * 8;
#pragma unroll
    for (int q = 0; q < 4; ++q) {
        float4 x0 = *(const float4*)(frow + q * 32);
        float4 x1 = *(const float4*)(frow + q * 32 + 4);
        float xs[8] = {x0.x, x0.y, x0.z, x0.w, x1.x, x1.y, x1.z, x1.w};
#pragma unroll
        for (int j = 0; j < 8; ++j) {
            unsigned short hh = f2bf(xs[j]);
            Fh[q][j] = (short)hh;
            Fl[q][j] = (short)f2bf(xs[j] - bf2f(hh));
        }
    }

#pragma unroll 1
    for (int tt = 0; tt < 8; ++tt) {
        floatx4 as = {0.f,0.f,0.f,0.f}, ad = {0.f,0.f,0.f,0.f}, av = {0.f,0.f,0.f,0.f};
#pragma unroll
        for (int q = 0; q < 4; ++q) {
            bf16x8 ws = *(const bf16x8*)(Bsw + ((((tt)      * 4 + q) * 64 + lane) << 3));
            bf16x8 wd = *(const bf16x8*)(Bsw + ((((8 + tt)  * 4 + q) * 64 + lane) << 3));
            bf16x8 wv = *(const bf16x8*)(Bsw + ((((16 + tt) * 4 + q) * 64 + lane) << 3));
            as = __builtin_amdgcn_mfma_f32_16x16x32_bf16(ws, Fh[q], as, 0, 0, 0);
            as = __builtin_amdgcn_mfma_f32_16x16x32_bf16(ws, Fl[q], as, 0, 0, 0);
            ad = __builtin_amdgcn_mfma_f32_16x16x32_bf16(wd, Fh[q], ad, 0, 0, 0);
            ad = __builtin_amdgcn_mfma_f32_16x16x32_bf16(wd, Fl[q], ad, 0, 0, 0);
            av = __builtin_amdgcn_mfma_f32_16x16x32_bf16(wv, Fh[q], av, 0, 0, 0);
            av = __builtin_amdgcn_mfma_f32_16x16x32_bf16(wv, Fl[q], av, 0, 0, 0);
        }
        int cbase = (tt << 4) + (quad << 2);
        float4 bs = *(const float4*)(b_src + cbase);
        float4 bd = *(const float4*)(b_dst + cbase);
        float4 bv = *(const float4*)(b_v   + cbase);
        uint4 o;
        o.x = pk(as[0] + bs.x * LOG2E, as[1] + bs.y * LOG2E);
        o.y = pk(av[0] + bv.x,         av[1] + bv.y);
        o.z = pk(as[2] + bs.z * LOG2E, as[3] + bs.w * LOG2E);
        o.w = pk(av[2] + bv.z,         av[3] + bv.w);
        *(uint4*)(gsv + node * 256 + (cbase << 1)) = o;
        uint2 od;
        od.x = pk(ad[0] + bd.x * LOG2E, ad[1] + bd.y * LOG2E);
        od.y = pk(ad[2] + bd.z * LOG2E, ad[3] + bd.w * LOG2E);
        *(uint2*)(fdh + node * 128 + cbase) = od;
    }
}

// ---------------------------------------------------------------------------
// K5: pass-2 bin. One block per bucket (256 dst nodes). Stages edges and the
// sorted result in LDS, flushes ssort coalesced. Emits off[] and ssort pads.
// ---------------------------------------------------------------------------
__global__ __launch_bounds__(256) void bin_kernel(
    const unsigned int* __restrict__ tmp, const int* __restrict__ HtabS,
    int* __restrict__ off, int* __restrict__ ssort) {
    __shared__ unsigned int ebuf[EBUF];
    __shared__ unsigned short obuf[EBUF];
    __shared__ int cnt_l[256];
    __shared__ int wsum[4];
    int b = blockIdx.x, t = threadIdx.x, lane = t & 63, w = t >> 6;
    int start = HtabS[b * NB1];
    int end = (b == NBUK - 1) ? N_EDGES : HtabS[(b + 1) * NB1];
    int cnt0 = end - start;
    cnt_l[t] = 0;
    __syncthreads();
    bool staged = (cnt0 <= EBUF);
    for (int i = t; i < cnt0; i += 256) {
        unsigned int e = tmp[start + i];
        if (staged) ebuf[i] = e;
        atomicAdd(&cnt_l[e >> 16], 1);
    }
    __syncthreads();
    int v = cnt_l[t];
    int x = v;
#pragma unroll
    for (int d = 1; d < 64; d <<= 1) { int up = __shfl_up(x, d); if (lane >= d) x += up; }
    if (lane == 63) wsum[w] = x;
    __syncthreads();
    int basex = 0;
    for (int ww = 0; ww < w; ++ww) basex += wsum[ww];
    int excl = basex + x - v;                  // exclusive within bucket
    int node = b * 256 + t;
    if (node < N_NODES) off[node] = start + excl;
    if (b == NBUK - 1) {
        if (t == 0) off[N_NODES] = N_EDGES;
        if (t < 4) ssort[N_EDGES + t] = 0;     // pads for gather prefetch
    }
    __syncthreads();
    cnt_l[t] = excl;                           // becomes cursor
    __syncthreads();
    if (staged) {
        for (int i = t; i < cnt0; i += 256) {
            unsigned int e = ebuf[i];
            int p = atomicAdd(&cnt_l[e >> 16], 1);
            obuf[p] = (unsigned short)(e & 0xFFFFu);
        }
        __syncthreads();
        for (int i = t; i < cnt0; i += 256)    // coalesced flush
            ssort[start + i] = (int)obuf[i];
    } else {
        for (int i = t; i < cnt0; i += 256) {
            unsigned int e = tmp[start + i];
            int p = atomicAdd(&cnt_l[e >> 16], 1);
            ssort[start + p] = (int)(e & 0xFFFFu);
        }
    }
}

// ---------------------------------------------------------------------------
// K6: gather. One wave per dst node; TWO edges per wave-iteration: half-wave
// per edge, each lane reads one dwordx4 = 4 channels {fs,fs,fv,fv}x2 of its
// edge's gsv row. Partials combined at the end via shfl_xor(32). fp32 logit
// math, exp2 (weights pre-scaled by log2e). float4 output stores.
// ---------------------------------------------------------------------------
__global__ __launch_bounds__(128) void gather_kernel(
    const unsigned short* __restrict__ gsv, const unsigned short* __restrict__ fdh,
    const int* __restrict__ off, const int* __restrict__ ssort,
    float* __restrict__ out, int n) {
    int wid = __builtin_amdgcn_readfirstlane((int)((blockIdx.x * 128 + threadIdx.x) >> 6));
    int lane = threadIdx.x & 63;
    if (wid >= n) return;
    int half = lane >> 5;                 // which edge of the current pair
    int grp = lane & 31;                  // channel group: 4*grp .. 4*grp+3
    uint2 fdraw = *(const uint2*)(fdh + (size_t)wid * 128 + grp * 4);
    float2 fd01 = __half22float2(*(const __half2*)&fdraw.x);
    float2 fd23 = __half22float2(*(const __half2*)&fdraw.y);

    float n0=0.f,n1=0.f,n2=0.f,n3=0.f,d0=0.f,d1=0.f,d2=0.f,d3=0.f;
    int beg = off[wid], end = off[wid + 1];
    int deg = end - beg;
    int iters = (deg + 1) >> 1;

#define EDGE_UPD4(g, valid) {                                                  \
    float2 fs01 = __half22float2(*(const __half2*)&(g).x);                     \
    float2 fv01 = __half22float2(*(const __half2*)&(g).y);                     \
    float2 fs23 = __half22float2(*(const __half2*)&(g).z);                     \
    float2 fv23 = __half22float2(*(const __half2*)&(g).w);                     \
    float a0 = fs01.x + fd01.x, a1 = fs01.y + fd01.y;                          \
    float a2 = fs23.x + fd23.x, a3 = fs23.y + fd23.y;                          \
    a0 = fmaf(fminf(a0, 0.f), -0.8f, a0);                                      \
    a1 = fmaf(fminf(a1, 0.f), -0.8f, a1);                                      \
    a2 = fmaf(fminf(a2, 0.f), -0.8f, a2);                                      \
    a3 = fmaf(fminf(a3, 0.f), -0.8f, a3);                                      \
    float x0 = EXP2F(a0), x1 = EXP2F(a1), x2 = EXP2F(a2), x3 = EXP2F(a3);      \
    if (!(valid)) { x0 = 0.f; x1 = 0.f; x2 = 0.f; x3 = 0.f; }                  \
    d0 += x0; d1 += x1; d2 += x2; d3 += x3;                                    \
    n0 = fmaf(x0, fv01.x, n0); n1 = fmaf(x1, fv01.y, n1);                      \
    n2 = fmaf(x2, fv23.x, n2); n3 = fmaf(x3, fv23.y, n3); }

    if (iters > 0) {
        int s = ssort[beg + half];
        uint4 g = *(const uint4*)(gsv + (size_t)s * 256 + grp * 8);
        for (int k = 0; k < iters - 1; ++k) {
            int s2 = ssort[beg + 2 * k + 2 + half];                  // <= E+3
            uint4 g2 = *(const uint4*)(gsv + (size_t)s2 * 256 + grp * 8);
            EDGE_UPD4(g, 1);
            g = g2;
        }
        EDGE_UPD4(g, (half == 0) | ((deg & 1) == 0));
    }
    d0 += __shfl_xor(d0, 32); d1 += __shfl_xor(d1, 32);
    d2 += __shfl_xor(d2, 32); d3 += __shfl_xor(d3, 32);
    n0 += __shfl_xor(n0, 32); n1 += __shfl_xor(n1, 32);
    n2 += __shfl_xor(n2, 32); n3 += __shfl_xor(n3, 32);
    if (half == 0) {
        float4 o;
        o.x = (d0 > 0.f) ? n0 / d0 : 0.f;
        o.y = (d1 > 0.f) ? n1 / d1 : 0.f;
        o.z = (d2 > 0.f) ? n2 / d2 : 0.f;
        o.w = (d3 > 0.f) ? n3 / d3 : 0.f;
        *(float4*)&out[(size_t)wid * HD + grp * 4] = o;
    }
#undef EDGE_UPD4
}

// ---------------------------------------------------------------------------
extern "C" void kernel_launch(void* const* d_in, const int* in_sizes, int n_in,
                              void* d_out, int out_size, void* d_ws, size_t ws_size,
                              hipStream_t stream) {
    const float* feat  = (const float*)d_in[0];
    const float* W_src = (const float*)d_in[1];
    const float* b_src = (const float*)d_in[2];
    const float* W_dst = (const float*)d_in[3];
    const float* b_dst = (const float*)d_in[4];
    const float* W_v   = (const float*)d_in[5];
    const float* b_v   = (const float*)d_in[6];
    const int*   src   = (const int*)d_in[7];
    const int*   dst   = (const int*)d_in[8];
    float* out = (float*)d_out;

    // workspace layout
    unsigned short* gsv  = (unsigned short*)d_ws;                // N*256 u16
    unsigned short* fdh  = gsv + (size_t)N_NODES * 256;          // N*128 u16
    unsigned short* Bsw  = fdh + (size_t)N_NODES * 128;          // 49152 u16
    unsigned short* Htab = Bsw + 24 * 4 * 64 * 8;                // MTAB u16
    int* HtabS = (int*)(Htab + MTAB);                            // MTAB+1 int
    int* bsum  = HtabS + MTAB + 1;                               // 256
    int* off   = bsum + 256;                                     // N+1
    int* ssort = off + (N_NODES + 1);                            // E+4
    unsigned int* tmp = (unsigned int*)(ssort + N_EDGES + 4);    // E

    prep_hist_kernel<<<PREPN + NB1, 256, 0, stream>>>(W_src, W_dst, W_v, Bsw, dst, Htab);

    scan_partial<<<MB_SCAN, 256, 0, stream>>>(Htab, bsum, MTAB);
    scan_write2<<<MB_SCAN, 256, 0, stream>>>(Htab, bsum, HtabS, MTAB, MB_SCAN);

    proj_scatter_kernel<<<PGRID + NB1, 256, 0, stream>>>(
        feat, Bsw, b_src, b_dst, b_v, gsv, fdh, src, dst, HtabS, tmp);

    bin_kernel<<<NBUK, 256, 0, stream>>>(tmp, HtabS, off, ssort);

    gather_kernel<<<(N_NODES * 64) / 128, 128, 0, stream>>>(gsv, fdh, off, ssort, out, N_NODES);
}